// Round 5
// baseline (5790.647 us; speedup 1.0000x reference)
//
#include <hip/hip_runtime.h>

// samx_qkv_1bit R5: BISECT — packing only, verbatim reference semantics.
//  - ONE u64 per SAM state: tr0[11:0] tr1[23:12] fl[35:24] ml[47:36] rlp1[59:48]
//    (0xFFF = absent/-1; rlp1 = r+1, 0 = none). Each walk level = 1 ds_read_b64.
//  - NO register caching of state words (R3/R4 suspect): every read fresh.
//  - NO direct tables, NO truncated propagation: loops are literal
//    transcriptions of the reference (incl. propagation early-stop).
//  - LDS = 4096*8 = 32768 B -> 5 blocks/CU capacity, 4 needed; all 1024 rows
//    (one per block) co-resident on 256 CUs.

#define NSTATES 4096
#define TLEN 2048

typedef unsigned long long u64;

__device__ __forceinline__ int fld(u64 w, int sh) { return (int)((w >> sh) & 0xFFFull); }

__global__ __launch_bounds__(64)
void samx_main(const float* __restrict__ q,
               const float* __restrict__ k,
               unsigned* __restrict__ outpos,
               int T, int C) {
  __shared__ u64 st[NSTATES];

  const int row = blockIdx.x;
  const int b = row / C;
  const int c = row - b * C;
  const int lane = threadIdx.x;

  for (int s = lane; s < NSTATES; s += 64) st[s] = 0x0000000FFFFFFFFFull;

  const size_t rowbase = (size_t)b * (size_t)T * (size_t)C + (size_t)c;
  const float* qr = q + rowbase;
  const float* kr = k + rowbase;
  unsigned* outr = outpos + rowbase;

  // Pre-binarize: lane L holds bits t = 32L..32L+31 of q and k.
  unsigned qw = 0u, kw = 0u;
  {
    const int t0 = lane * 32;
#pragma unroll 8
    for (int jj = 0; jj < 32; ++jj) {
      const int t = t0 + jj;
      if (qr[(size_t)t * C] > 0.0f) qw |= (1u << jj);
      if (kr[(size_t)t * C] > 0.0f) kw |= (1u << jj);
    }
  }
  __syncthreads();
  if (lane != 0) return;

  int g = 0;  // last state
  int u = 1;  // next free state id
  int w = 0;  // query-match state
  int h = 0;  // query-match length

  for (int i = 0; i < T; ++i) {
    const unsigned qwi = (unsigned)__builtin_amdgcn_readlane((int)qw, i >> 5);
    const unsigned kwi = (unsigned)__builtin_amdgcn_readlane((int)kw, i >> 5);
    const int qs = (int)((qwi >> (i & 31)) & 1u);
    const int ks = (int)((kwi >> (i & 31)) & 1u);
    const int qsh = qs ? 12 : 0;
    const int ksh = ks ? 12 : 0;

    // ---- query: extend match with symbol qs (verbatim) ----
    int p = w, x = h;
    int ttrans = -1;
    for (;;) {
      if (p == 0xFFF) break;
      const u64 pw = st[p];
      const int t = fld(pw, qsh);
      if (t != 0xFFF) { ttrans = t; break; }
      const int mp = fld(pw, 36);
      if (x > mp) x = mp;
      p = fld(pw, 24);
    }
    if (p != 0xFFF) { p = ttrans; x = x + 1; }
    else            { p = 0;      x = 0; }

    // ---- tightest state for match length x (verbatim, read-only phase) ----
    int vst = p;
    for (;;) {
      const u64 vw = st[vst];
      const int fv = fld(vw, 24);
      if (fv == 0xFFF) break;
      const u64 fw = st[fv];
      if (fld(fw, 36) < x) break;
      vst = fv;
    }
    // ---- back off to positive length + recorded endpos (verbatim) ----
    for (;;) {
      if (vst == 0xFFF) break;
      const u64 vw = st[vst];
      if (fld(vw, 36) > 0 && fld(vw, 48) != 0) break;
      vst = fld(vw, 24);
    }
    unsigned vidx = 0u;  // 0 = no match -> y = 0
    if (vst != 0xFFF) vidx = (unsigned)fld(st[vst], 48);  // r+1
    outr[(size_t)i * C] = vidx;  // fire-and-forget
    w = p; h = x;

    // ---- key: SAM extension with symbol ks (verbatim, fresh reads) ----
    const int j = u++;
    const int mlj = fld(st[g], 36) + 1;
    int p2 = g;
    int d = -1;
    for (;;) {
      if (p2 == 0xFFF) break;
      const u64 pw2 = st[p2];
      const int t = fld(pw2, ksh);
      if (t != 0xFFF) { d = t; break; }
      st[p2] = (pw2 & ~(0xFFFull << ksh)) | ((u64)j << ksh);  // tk[p2] = j
      p2 = fld(pw2, 24);
    }

    int flj;
    if (p2 == 0xFFF) {
      flj = 0;
    } else {
      const u64 dw = st[d];
      const int mld = fld(dw, 36);
      const int mlp = fld(st[p2], 36);
      if (mlp + 1 == mld) {
        flj = d;
      } else {
        const int bb = u++;  // clone of d with length mlp+1
        const u64 bw = (dw & ~(0xFFFull << 36)) | ((u64)(mlp + 1) << 36);
        st[bb] = bw;                                          // tr,fl,rl copied
        st[d] = (dw & ~(0xFFFull << 24)) | ((u64)bb << 24);   // fl[d] = bb
        flj = bb;
        // redirect: while tk[p] == d: tk[p] = bb, p = fl[p]  (fresh reads)
        int p3 = p2;
        for (;;) {
          if (p3 == 0xFFF) break;
          const u64 pw3 = st[p3];
          if (fld(pw3, ksh) != d) break;
          st[p3] = (pw3 & ~(0xFFFull << ksh)) | ((u64)bb << ksh);
          p3 = fld(pw3, 24);
        }
      }
    }
    // j's word: no transitions, fl=flj, ml=mlj, rlp1=0 (set by propagation)
    st[j] = 0xFFFFFFull | ((u64)flj << 24) | ((u64)mlj << 36);
    g = j;

    // ---- endpos propagation (verbatim incl. early stop) ----
    {
      int vp = j;
      for (;;) {
        if (vp == 0xFFF) break;
        const u64 vw = st[vp];
        if (fld(vw, 48) >= i + 1) break;  // r[vp] >= i
        st[vp] = (vw & ~(0xFFFull << 48)) | ((u64)(i + 1) << 48);
        vp = fld(vw, 24);
      }
    }
  }
}

// Fully parallel epilogue: vidx (u32, = r+1, 0 = no match) -> sign*e.
__global__ __launch_bounds__(256)
void samx_epilogue(const float* __restrict__ v,
                   const float* __restrict__ e,
                   unsigned* __restrict__ out,
                   int T, int C, int total) {
  const int idx = blockIdx.x * 256 + threadIdx.x;
  if (idx >= total) return;
  const unsigned vidx = out[idx];
  const int c = idx % C;
  const int bi = idx / C;
  const int b = bi / T;
  const float ev = e[c];
  float val = -ev;  // y=0
  if (vidx != 0u) {
    if (v[((size_t)b * (size_t)T + (size_t)vidx) * (size_t)C + (size_t)c] > 0.0f)
      val = ev;
  }
  out[idx] = __float_as_uint(val);
}

extern "C" void kernel_launch(void* const* d_in, const int* in_sizes, int n_in,
                              void* d_out, int out_size, void* d_ws, size_t ws_size,
                              hipStream_t stream) {
  const float* q = (const float*)d_in[0];
  const float* k = (const float*)d_in[1];
  const float* v = (const float*)d_in[2];
  const float* e = (const float*)d_in[3];

  const int C = in_sizes[3];
  const int T = TLEN;
  const int B = in_sizes[0] / (T * C);
  const int total = out_size;

  samx_main<<<dim3(B * C), dim3(64), 0, stream>>>(q, k, (unsigned*)d_out, T, C);
  samx_epilogue<<<dim3((total + 255) / 256), dim3(256), 0, stream>>>(
      v, e, (unsigned*)d_out, T, C, total);
}

// Round 7
// 4113.635 us; speedup vs baseline: 1.4077x; 1.4077x over previous
//
#include <hip/hip_runtime.h>

// samx_qkv_1bit R7: split-array layout (R2-proven) + single-LDS-wait walk
// levels. Per-state fields:
//   tr0/tr1: u16[4096], transition targets, 0xFFFF = absent (blind stores)
//   flml:    u32[4096], fl in [15:0] (0xFFFF = -1), ml in [31:16]
//            (written ONLY at state creation / clone / fl[d]=clone; no RMW
//             in walks -> walks are pure loads + blind u16 stores)
//   rl:      u16[4096], last end pos, 0xFFFF = -1 (blind stores)
// Every walk level issues ALL its loads before the branch -> one lgkmcnt
// wait per level (R2 had up to two serial waits per level).
// Propagation early-stop removed: r is only ever set to the current step
// index and steps strictly increase, so r[vp] < i always holds (R5-verified
// semantics preserved).
// LDS: 8192+8192+16384+8192 = 40960 B -> 4 blocks/CU, all 1024 rows
// (one per block) co-resident on 256 CUs. No table, no truncation, no
// cross-step register caching of mutable LDS state (R3/R4/R6 lessons).

#define NSTATES 4096
#define TLEN 2048

__global__ __launch_bounds__(64)
void samx_main(const float* __restrict__ q,
               const float* __restrict__ k,
               unsigned* __restrict__ outpos,
               int T, int C) {
  __shared__ unsigned short tr0[NSTATES];
  __shared__ unsigned short tr1[NSTATES];
  __shared__ unsigned       flml[NSTATES];
  __shared__ unsigned short rl[NSTATES];

  const int row = blockIdx.x;
  const int b = row / C;
  const int c = row - b * C;
  const int lane = threadIdx.x;

  for (int s = lane; s < NSTATES; s += 64) {
    tr0[s] = 0xFFFFu; tr1[s] = 0xFFFFu;
    flml[s] = 0x0000FFFFu;  // fl=-1, ml=0
    rl[s] = 0xFFFFu;
  }

  const size_t rowbase = (size_t)b * (size_t)T * (size_t)C + (size_t)c;
  const float* qr = q + rowbase;
  const float* kr = k + rowbase;
  unsigned* outr = outpos + rowbase;

  // Pre-binarize: lane L holds bits t = 32L..32L+31 of q and k.
  unsigned qw = 0u, kw = 0u;
  {
    const int t0 = lane * 32;
#pragma unroll 8
    for (int jj = 0; jj < 32; ++jj) {
      const int t = t0 + jj;
      if (qr[(size_t)t * C] > 0.0f) qw |= (1u << jj);
      if (kr[(size_t)t * C] > 0.0f) kw |= (1u << jj);
    }
  }
  __syncthreads();
  if (lane != 0) return;

  int g = 0;    // last state
  int mlg = 0;  // ml[g] (register dataflow: ml of existing states never changes)
  int u = 1;    // next free state id
  int w = 0;    // query-match state
  int h = 0;    // query-match length

  for (int i = 0; i < T; ++i) {
    const unsigned qwi = (unsigned)__builtin_amdgcn_readlane((int)qw, i >> 5);
    const unsigned kwi = (unsigned)__builtin_amdgcn_readlane((int)kw, i >> 5);
    const int qs = (int)((qwi >> (i & 31)) & 1u);
    const int ks = (int)((kwi >> (i & 31)) & 1u);
    unsigned short* tq = qs ? tr1 : tr0;
    unsigned short* tk = ks ? tr1 : tr0;

    // ---- query: extend match with symbol qs ----
    // Level: load tq[p] and flml[p] together, then branch (one wait).
    int p = w, x = h;
    int pnew, xnew;
    for (;;) {
      if (p == -1) { pnew = 0; xnew = 0; break; }
      const int t = (int)(short)tq[p];
      const unsigned fm = flml[p];
      if (t != -1) { pnew = t; xnew = x + 1; break; }
      const int mp = (int)(fm >> 16);
      if (x > mp) x = mp;
      p = (int)(short)(fm & 0xFFFFu);
    }
    p = pnew; x = xnew;

    // ---- tightest state for match length x (carry parent word) ----
    int vst = p;
    unsigned fmv = flml[vst];
    for (;;) {
      const int fv = (int)(short)(fmv & 0xFFFFu);
      if (fv == -1) break;
      const unsigned fmf = flml[fv];
      if ((int)(fmf >> 16) < x) break;
      vst = fv; fmv = fmf;
    }
    // ---- back off to positive length + recorded endpos ----
    int rv = -1;
    for (;;) {
      if (vst == -1) { rv = -1; break; }
      const unsigned fm2 = flml[vst];
      const int r2 = (int)(short)rl[vst];
      if ((int)(fm2 >> 16) > 0 && r2 >= 0) { rv = r2; break; }
      vst = (int)(short)(fm2 & 0xFFFFu);
    }
    outr[(size_t)i * C] = (unsigned)(rv + 1);  // 0 = no match
    w = p; h = x;

    // ---- key: SAM extension with symbol ks ----
    const int j = u++;
    const int mlj = mlg + 1;
    int p2 = g;
    int d = -1;
    unsigned fmp2 = 0;  // flml of the breaking node (valid when d != -1)
    for (;;) {
      if (p2 == -1) break;
      const int t = (int)(short)tk[p2];
      const unsigned fm = flml[p2];
      if (t != -1) { d = t; fmp2 = fm; break; }
      tk[p2] = (unsigned short)j;  // blind store
      p2 = (int)(short)(fm & 0xFFFFu);
    }

    int flj;
    if (d == -1) {
      flj = 0;
    } else {
      const unsigned fmd = flml[d];
      const int mld = (int)(fmd >> 16);
      const int mlp = (int)(fmp2 >> 16);
      if (mlp + 1 == mld) {
        flj = d;
      } else {
        const int bb = u++;  // clone of d with length mlp+1
        tr0[bb] = tr0[d];
        tr1[bb] = tr1[d];
        rl[bb] = rl[d];
        flml[bb] = (fmd & 0xFFFFu) | ((unsigned)(mlp + 1) << 16);  // fl=fl[d]
        flml[d]  = (fmd & 0xFFFF0000u) | (unsigned)bb;             // fl[d]=bb
        flj = bb;
        // redirect: while tk[p] == d: tk[p] = bb, p = fl[p]
        int p3 = p2;
        for (;;) {
          if (p3 == -1) break;
          const int t3 = (int)(short)tk[p3];
          const unsigned fm3 = flml[p3];
          if (t3 != d) break;
          tk[p3] = (unsigned short)bb;  // blind store
          p3 = (int)(short)(fm3 & 0xFFFFu);
        }
      }
    }
    flml[j] = (unsigned)(flj & 0xFFFF) | ((unsigned)mlj << 16);
    g = j; mlg = mlj;

    // ---- endpos propagation: full chain, blind rl stores ----
    // (early-stop removed: r values are only ever set to the current step
    //  index and i strictly increases, so r[vp] < i always.)
    {
      int vp = j;
      for (;;) {
        rl[vp] = (unsigned short)i;  // blind store
        const int fv = (int)(short)(flml[vp] & 0xFFFFu);
        if (fv == -1) break;
        vp = fv;
      }
    }
  }
}

// Fully parallel epilogue: vidx (u32, = r+1, 0 = no match) -> sign*e.
__global__ __launch_bounds__(256)
void samx_epilogue(const float* __restrict__ v,
                   const float* __restrict__ e,
                   unsigned* __restrict__ out,
                   int T, int C, int total) {
  const int idx = blockIdx.x * 256 + threadIdx.x;
  if (idx >= total) return;
  const unsigned vidx = out[idx];
  const int c = idx % C;
  const int bi = idx / C;
  const int b = bi / T;
  const float ev = e[c];
  float val = -ev;  // y=0
  if (vidx != 0u) {
    if (v[((size_t)b * (size_t)T + (size_t)vidx) * (size_t)C + (size_t)c] > 0.0f)
      val = ev;
  }
  out[idx] = __float_as_uint(val);
}

extern "C" void kernel_launch(void* const* d_in, const int* in_sizes, int n_in,
                              void* d_out, int out_size, void* d_ws, size_t ws_size,
                              hipStream_t stream) {
  const float* q = (const float*)d_in[0];
  const float* k = (const float*)d_in[1];
  const float* v = (const float*)d_in[2];
  const float* e = (const float*)d_in[3];

  const int C = in_sizes[3];
  const int T = TLEN;
  const int B = in_sizes[0] / (T * C);
  const int total = out_size;

  samx_main<<<dim3(B * C), dim3(64), 0, stream>>>(q, k, (unsigned*)d_out, T, C);
  samx_epilogue<<<dim3((total + 255) / 256), dim3(256), 0, stream>>>(
      v, e, (unsigned*)d_out, T, C, total);
}